// Round 3
// baseline (187.166 us; speedup 1.0000x reference)
//
#include <hip/hip_runtime.h>

// Conv2d 3x3 pad1 stride1, x[1,256,224,224] f32, w[256,256,3,3] f32 -> out[256,224,224] f32
// Implicit GEMM: M=256 (co), N=50176 (h*224+w), K=2304 (tap-major: k = (dh*3+dw)*256 + ci)
// R9: T3+T4+T5 port. BM=256 (all M) x BN=256, 8 waves (2M x 4N), wave-tile 128x64,
//     acc[8][4]. BK=32, TRIPLE-buffered LDS (3 x 32KB), 2 sub-phases per K-tile
//     (16 MFMA each), raw s_barrier + counted vmcnt(4) (never 0 in main loop) +
//     lgkmcnt(0)+sched_barrier(0) + setprio around MFMA clusters. Grid 196 x 512thr.
//     Fragment layout + chunk-XOR swizzle identical to proven R7/R8 kernel.

#define H 224
#define W 224
#define NPOS (H*W)          // 50176
#define CI 256
#define CO 256
#define KDIM 2304
#define HP 226              // padded
#define XP_ELEMS (HP*HP*CI) // 13,075,456 shorts
#define AP_ELEMS (CO*KDIM)  // 589,824 shorts

typedef __bf16 bf16x8 __attribute__((ext_vector_type(8)));
typedef float f32x4 __attribute__((ext_vector_type(4)));
typedef unsigned short u16x4 __attribute__((ext_vector_type(4)));
typedef unsigned short u16x8 __attribute__((ext_vector_type(8)));

__device__ __forceinline__ unsigned short f2bf(float f) {
    unsigned int u = __float_as_uint(f);
    u += 0x7fff + ((u >> 16) & 1);   // round-to-nearest-even
    return (unsigned short)(u >> 16);
}

__device__ __forceinline__ void load_lds16(const unsigned short* g, unsigned short* l) {
    __builtin_amdgcn_global_load_lds(
        (const __attribute__((address_space(1))) void*)g,
        (__attribute__((address_space(3))) void*)l,
        16, 0, 0);
}

// ---- fused prep (unchanged from R8): xtrans + weight transform + border zero ----
#define XT_BLOCKS 3136      // 784 * 4
#define WT_BLOCKS 256
#define BORDER_V8 28800     // 230,400 shorts / 8
#define ROW_V8 7232         // 226*256/8
__global__ void prep_kernel(const float* __restrict__ x, const float* __restrict__ w,
                            unsigned short* __restrict__ ap, unsigned short* __restrict__ xp) {
    __shared__ unsigned short smem[64 * 68];
    const int bx = blockIdx.x;
    const int t = threadIdx.x;

    if (bx < XT_BLOCKS) {
        const unsigned int pBase = (unsigned int)(bx % 784) * 64;
        const unsigned int ciBase = (unsigned int)(bx / 784) * 64;
        {
            const int p4 = (t & 15) * 4;
            const int c0 = t >> 4;               // 0..15
#pragma unroll
            for (int i = 0; i < 4; ++i) {
                const int ci_l = c0 + i * 16;
                const f32x4 v = *(const f32x4*)&x[(ciBase + ci_l) * NPOS + pBase + p4];
                u16x4 s;
                s[0] = f2bf(v[0]); s[1] = f2bf(v[1]); s[2] = f2bf(v[2]); s[3] = f2bf(v[3]);
                *(u16x4*)&smem[ci_l * 68 + p4] = s;
            }
        }
        __syncthreads();
        {
            const int ci0 = (t & 7) * 8;
            const int pr = t >> 3;               // 0..31
#pragma unroll
            for (int j = 0; j < 2; ++j) {
                const int p_l = pr + j * 32;
                const unsigned int p = pBase + p_l;
                const unsigned int hi = p / W, wi = p - hi * W;
                u16x8 v;
#pragma unroll
                for (int k = 0; k < 8; ++k) v[k] = smem[(ci0 + k) * 68 + p_l];
                *(u16x8*)&xp[((hi + 1) * HP + (wi + 1)) * CI + ciBase + ci0] = v;
            }
        }
    } else if (bx < XT_BLOCKS + WT_BLOCKS) {
        const int co = bx - XT_BLOCKS;
        const float* wc = w + co * KDIM;
#pragma unroll
        for (int i = 0; i < 9; ++i)
            smem[i * 256 + t] = f2bf(wc[i * 256 + t]);
        __syncthreads();
        unsigned short* apc = ap + co * KDIM;
#pragma unroll
        for (int tap = 0; tap < 9; ++tap)
            apc[tap * 256 + t] = smem[t * 9 + tap];
    } else {
        const int idx = (bx - XT_BLOCKS - WT_BLOCKS) * 256 + t;
        if (idx < BORDER_V8) {
            unsigned short* p;
            if (idx < 2 * ROW_V8) {
                const int r = idx / ROW_V8;
                const int off = idx - r * ROW_V8;
                p = xp + r * (225 * HP * CI) + off * 8;
            } else {
                const int i2 = idx - 2 * ROW_V8;
                const int seg = i2 >> 5;
                const int o = i2 & 31;
                const int hp = 1 + (seg >> 1);
                const int wp = (seg & 1) * 225;
                p = xp + (hp * HP + wp) * CI + o * 8;
            }
            *(u16x8*)p = (u16x8){0, 0, 0, 0, 0, 0, 0, 0};
        }
    }
}

// ---- implicit GEMM, 256x256 tile, 8 waves, triple-buffer BK=32, counted vmcnt ----
// LDS per buffer: A 256rows x 32k (16KB) + B 256rows x 32k (16KB). 3 buffers = 96KB.
// Per K-tile per wave: ph1 {ldA mi0-3 (4 b128) + ldB (4 b128); stageA(kt+2); bar;
//   lgkm0; 16 MFMA; bar}  ph2 {ldA mi4-7; stageB(kt+2); vmcnt(4); bar; lgkm0;
//   16 MFMA; bar}.  vmcnt(4) proof: per-thread 4 loads/K-tile (2 ph1 + 2 ph2);
//   newest 4 at the wait are kt+2's, so kt+1's stages have landed; buffer (kt+2)%3
//   was last read during kt-1, so stage-issue at kt is after its readers' barrier.
__global__ __launch_bounds__(512, 1) void gemm_conv_kernel(
    const unsigned short* __restrict__ Ap,   // [256][2304] bf16
    const unsigned short* __restrict__ Xp,   // [226][226][256] bf16
    float* __restrict__ out)                 // [256][50176]
{
    __shared__ unsigned short Als[3][8192];  // [buf][256 rows x 32]
    __shared__ unsigned short Bls[3][8192];

    const int tid = threadIdx.x;
    const int Nb = blockIdx.x;               // 0..195
    const int wave = tid >> 6;               // 0..7
    const int wm = wave >> 2;                // 0..1 (M half: 128 rows)
    const int wn = wave & 3;                 // 0..3 (N quarter: 64 cols)
    const int lane = tid & 63;
    const int ln15 = lane & 15;
    const int quad = lane >> 4;
    const int xsw = ((quad ^ (ln15 & 3)) * 8);   // chunk-XOR swizzle on read

    // ---- staging sources: 2 A-chunks + 2 B-chunks per thread per K-tile ----
    const int rl = lane >> 2;                // 0..15
    const int sc = (lane & 3) ^ (rl & 3);    // swizzled source chunk

    const unsigned short* a_src[2];
    const unsigned short* b_src[2];
#pragma unroll
    for (int j = 0; j < 2; ++j) {
        const int row = j * 128 + wave * 16 + rl;          // 0..255
        a_src[j] = Ap + row * KDIM + sc * 8;               // + kt*32
        unsigned int p = Nb * 256 + row;
        unsigned int hi = p / W, wi = p - hi * W;
        b_src[j] = Xp + (hi * HP + wi) * CI + sc * 8;      // + tap/ci offset
    }

    f32x4 acc[8][4];
#pragma unroll
    for (int mi = 0; mi < 8; ++mi)
#pragma unroll
        for (int ni = 0; ni < 4; ++ni)
            acc[mi][ni] = (f32x4){0.f, 0.f, 0.f, 0.f};

    auto stageA = [&](int kt, int buf) {
        const int aoff = kt * 32;
#pragma unroll
        for (int j = 0; j < 2; ++j)
            load_lds16(a_src[j] + aoff, &Als[buf][(j * 8 + wave) * 512]);
    };
    auto stageB = [&](int kt, int buf) {
        const int tap = kt >> 3;             // 0..8 (8 K-tiles per tap)
        const int dh = tap / 3, dw = tap - dh * 3;
        const int boff = (dh * HP + dw) * CI + (kt & 7) * 32;
#pragma unroll
        for (int j = 0; j < 2; ++j)
            load_lds16(b_src[j] + boff, &Bls[buf][(j * 8 + wave) * 512]);
    };

    bf16x8 af[4], bfr[4];
    const int aBase = (wm * 128 + ln15) * 32 + xsw;        // + (half*64 + mi*16)*32
    const int bBase = (wn * 64 + ln15) * 32 + xsw;         // + ni*16*32

    auto ldA = [&](int c, int half) {
#pragma unroll
        for (int mi = 0; mi < 4; ++mi)
            af[mi] = *(const bf16x8*)&Als[c][aBase + (half * 64 + mi * 16) * 32];
    };
    auto ldB = [&](int c) {
#pragma unroll
        for (int ni = 0; ni < 4; ++ni)
            bfr[ni] = *(const bf16x8*)&Bls[c][bBase + ni * 16 * 32];
    };
    auto mfma16 = [&](int half) {
        __builtin_amdgcn_s_setprio(1);
#pragma unroll
        for (int mi = 0; mi < 4; ++mi)
#pragma unroll
            for (int ni = 0; ni < 4; ++ni)
                acc[half * 4 + mi][ni] = __builtin_amdgcn_mfma_f32_16x16x32_bf16(
                    af[mi], bfr[ni], acc[half * 4 + mi][ni], 0, 0, 0);
        __builtin_amdgcn_s_setprio(0);
    };

    // ---- prologue: fill buffers 0,1; wait for tile 0 only ----
    stageA(0, 0); stageB(0, 0);
    stageA(1, 1); stageB(1, 1);
    asm volatile("s_waitcnt vmcnt(4)" ::: "memory");       // A(0),B(0) landed
    __builtin_amdgcn_s_barrier();

    int c = 0;                                             // kt % 3
    for (int kt = 0; kt < 70; ++kt) {
        const int s = (c == 0) ? 2 : c - 1;                // (kt+2) % 3
        // ---- phase 1: mi 0-3 ----
        ldA(c, 0); ldB(c);
        stageA(kt + 2, s);
        __builtin_amdgcn_s_barrier();
        asm volatile("s_waitcnt lgkmcnt(0)" ::: "memory");
        __builtin_amdgcn_sched_barrier(0);
        mfma16(0);
        __builtin_amdgcn_s_barrier();
        // ---- phase 2: mi 4-7 ----
        ldA(c, 1);
        stageB(kt + 2, s);
        asm volatile("s_waitcnt vmcnt(4)" ::: "memory");   // tile kt+1 fully landed
        __builtin_amdgcn_s_barrier();
        asm volatile("s_waitcnt lgkmcnt(0)" ::: "memory");
        __builtin_amdgcn_sched_barrier(0);
        mfma16(1);
        __builtin_amdgcn_s_barrier();
        c = (c == 2) ? 0 : c + 1;
    }
    // ---- kt = 70: no staging; drain so tile 71 is landed ----
    {
        ldA(c, 0); ldB(c);
        __builtin_amdgcn_s_barrier();
        asm volatile("s_waitcnt lgkmcnt(0)" ::: "memory");
        __builtin_amdgcn_sched_barrier(0);
        mfma16(0);
        __builtin_amdgcn_s_barrier();
        ldA(c, 1);
        asm volatile("s_waitcnt vmcnt(0)" ::: "memory");
        __builtin_amdgcn_s_barrier();
        asm volatile("s_waitcnt lgkmcnt(0)" ::: "memory");
        __builtin_amdgcn_sched_barrier(0);
        mfma16(1);
        __builtin_amdgcn_s_barrier();
        c = (c == 2) ? 0 : c + 1;
    }
    // ---- kt = 71: all resident, no LDS writers remain -> barrier-free ----
    {
        ldA(c, 0); ldB(c);
        asm volatile("s_waitcnt lgkmcnt(0)" ::: "memory");
        __builtin_amdgcn_sched_barrier(0);
        mfma16(0);
        ldA(c, 1);
        asm volatile("s_waitcnt lgkmcnt(0)" ::: "memory");
        __builtin_amdgcn_sched_barrier(0);
        mfma16(1);
    }

    // ---- epilogue: C/D layout col = lane&15 (n=p), row = quad*4 + reg (m=co) ----
    const int pcol = Nb * 256 + wn * 64 + ln15;
    const int corow = wm * 128 + quad * 4;
#pragma unroll
    for (int mi = 0; mi < 8; ++mi)
#pragma unroll
        for (int ni = 0; ni < 4; ++ni)
#pragma unroll
            for (int r = 0; r < 4; ++r)
                out[(corow + mi * 16 + r) * NPOS + pcol + ni * 16] = acc[mi][ni][r];
}

extern "C" void kernel_launch(void* const* d_in, const int* in_sizes, int n_in,
                              void* d_out, int out_size, void* d_ws, size_t ws_size,
                              hipStream_t stream) {
    const float* x = (const float*)d_in[0];       // [1,256,224,224]
    const float* w = (const float*)d_in[1];       // [256,256,3,3]
    float* out = (float*)d_out;                   // [256,224,224]

    unsigned short* xp = (unsigned short*)d_ws;        // 13,075,456 shorts
    unsigned short* ap = xp + XP_ELEMS;                // 589,824 shorts

    prep_kernel<<<XT_BLOCKS + WT_BLOCKS + 113, 256, 0, stream>>>(x, w, ap, xp);
    gemm_conv_kernel<<<dim3(NPOS / 256), 512, 0, stream>>>(ap, xp, out);
}